// Round 4
// baseline (4581.031 us; speedup 1.0000x reference)
//
#include <hip/hip_runtime.h>
#include <hip/hip_bf16.h>
#include <cstdint>
#include <cstddef>

#define DNODE 64
#define HDIM 256
#define NLAYERS 3

typedef __attribute__((ext_vector_type(8))) short bf16x8;
typedef __attribute__((ext_vector_type(4))) float f32x4;

__device__ __forceinline__ ushort f2bf(float f) {
    __hip_bfloat16 b = __float2bfloat16(f);
    return *(ushort*)&b;
}
__device__ __forceinline__ float bf2f(ushort u) {
    return __uint_as_float((uint32_t)u << 16);
}
__device__ __forceinline__ unsigned char f2fp8(float f) {
    int p = __builtin_amdgcn_cvt_pk_fp8_f32(f, f, 0, false);
    return (unsigned char)(p & 0xFF);
}

// ---------------------------------------------------------------------------
// CSR build: deg histogram -> exclusive scan -> fill col by atomic cursor
// ---------------------------------------------------------------------------

__global__ __launch_bounds__(256) void k_deg(const int* __restrict__ dst, int* __restrict__ deg, int E) {
    int e = blockIdx.x * 256 + threadIdx.x;
    if (e < E) atomicAdd(&deg[dst[e]], 1);
}

__global__ __launch_bounds__(256) void k_scan_partial(const int* __restrict__ deg, int* __restrict__ bsum, int n) {
    __shared__ int sd[256];
    int tid = threadIdx.x;
    int base = blockIdx.x * 2048 + tid * 8;
    int s = 0;
#pragma unroll
    for (int j = 0; j < 8; j++) {
        int idx = base + j;
        if (idx < n) s += deg[idx];
    }
    sd[tid] = s;
    __syncthreads();
    for (int off = 128; off > 0; off >>= 1) {
        if (tid < off) sd[tid] += sd[tid + off];
        __syncthreads();
    }
    if (tid == 0) bsum[blockIdx.x] = sd[0];
}

__global__ void k_scan_bsum(int* bsum, int nb) {
    if (threadIdx.x == 0 && blockIdx.x == 0) {
        int run = 0;
        for (int i = 0; i < nb; i++) { int v = bsum[i]; bsum[i] = run; run += v; }
    }
}

__global__ __launch_bounds__(256) void k_scan_final(const int* __restrict__ deg, const int* __restrict__ bsum,
                                                    int* __restrict__ row_ptr, int* __restrict__ cursor,
                                                    float* __restrict__ inv_den, int n, int Etot) {
    __shared__ int tsum[256];
    int tid = threadIdx.x;
    int base = blockIdx.x * 2048 + tid * 8;
    int loc[8], dv[8];
    int s = 0;
#pragma unroll
    for (int j = 0; j < 8; j++) {
        int idx = base + j;
        int v = (idx < n) ? deg[idx] : 0;
        dv[j] = v;
        loc[j] = s;
        s += v;
    }
    tsum[tid] = s;
    __syncthreads();
    for (int off = 1; off < 256; off <<= 1) {
        int t = (tid >= off) ? tsum[tid - off] : 0;
        __syncthreads();
        tsum[tid] += t;
        __syncthreads();
    }
    int off0 = bsum[blockIdx.x] + (tid ? tsum[tid - 1] : 0);
#pragma unroll
    for (int j = 0; j < 8; j++) {
        int idx = base + j;
        if (idx < n) {
            int rp = off0 + loc[j];
            row_ptr[idx] = rp;
            cursor[idx] = rp;
            int d = dv[j];
            inv_den[idx] = 1.0f / (float)(d > 0 ? d : 1);
        }
    }
    if (blockIdx.x == 0 && tid == 0) row_ptr[n] = Etot;
}

__global__ __launch_bounds__(256) void k_fill(const int* __restrict__ src, const int* __restrict__ dst,
                                              int* __restrict__ cursor, int* __restrict__ col, int E) {
    int e = blockIdx.x * 256 + threadIdx.x;
    if (e < E) {
        int p = atomicAdd(&cursor[dst[e]], 1);
        col[p] = src[e];
    }
}

// ---------------------------------------------------------------------------
// Converters: x -> bf16;  W[K][256] fp32 -> Wt[256][K] bf16 (B^T for MFMA)
// ---------------------------------------------------------------------------
__global__ __launch_bounds__(256) void k_xconv(const float* __restrict__ x, ushort* __restrict__ xb, int n4) {
    int i = blockIdx.x * 256 + threadIdx.x;
    if (i >= n4) return;
    float4 v = *(const float4*)&x[(size_t)i * 4];
    ushort4 o;
    o.x = f2bf(v.x); o.y = f2bf(v.y); o.z = f2bf(v.z); o.w = f2bf(v.w);
    *(ushort4*)&xb[(size_t)i * 4] = o;
}

__global__ __launch_bounds__(256) void k_wconv(const float* __restrict__ src, ushort* __restrict__ dst, int K) {
    int n = threadIdx.x;
    int k0 = blockIdx.x * 16;
#pragma unroll
    for (int i = 0; i < 16; i++) {
        int k = k0 + i;
        dst[(size_t)n * K + k] = f2bf(src[(size_t)k * 256 + n]);
    }
}

// ---------------------------------------------------------------------------
// Node-proj MFMA GEMM: H[M][256] = A[M][K] @ Bt[256][K]^T + bias
// 64x64 tile, 4 waves; writes bf16 H and fp8 mirror H8.
// ---------------------------------------------------------------------------
__global__ __launch_bounds__(256) void k_gemm_mfma(const ushort* __restrict__ A,
                                                   const ushort* __restrict__ Bt,
                                                   const float* __restrict__ bias,
                                                   ushort* __restrict__ H,
                                                   unsigned char* __restrict__ H8,
                                                   int M, int K) {
    __shared__ ushort As[64][40];
    __shared__ ushort Bs[64][40];
    int tid = threadIdx.x;
    int w = tid >> 6, l = tid & 63;
    int row0 = blockIdx.y * 64, col0 = blockIdx.x * 64;
    int sr = tid >> 2, sc = (tid & 3) * 8;
    int wm = (w >> 1) * 32, wn = (w & 1) * 32;
    int fr = l & 15, fk = (l >> 4) * 8;
    f32x4 acc[2][2] = {};

    for (int k0 = 0; k0 < K; k0 += 32) {
        bf16x8 av = {0, 0, 0, 0, 0, 0, 0, 0};
        int gr = row0 + sr;
        if (gr < M) av = *(const bf16x8*)&A[(size_t)gr * K + k0 + sc];
        *(bf16x8*)&As[sr][sc] = av;
        bf16x8 bv = *(const bf16x8*)&Bt[(size_t)(col0 + sr) * K + k0 + sc];
        *(bf16x8*)&Bs[sr][sc] = bv;
        __syncthreads();
        bf16x8 af[2], bf[2];
#pragma unroll
        for (int mi = 0; mi < 2; mi++) af[mi] = *(const bf16x8*)&As[wm + mi * 16 + fr][fk];
#pragma unroll
        for (int ni = 0; ni < 2; ni++) bf[ni] = *(const bf16x8*)&Bs[wn + ni * 16 + fr][fk];
#pragma unroll
        for (int mi = 0; mi < 2; mi++)
#pragma unroll
            for (int ni = 0; ni < 2; ni++)
                acc[mi][ni] = __builtin_amdgcn_mfma_f32_16x16x32_bf16(af[mi], bf[ni], acc[mi][ni], 0, 0, 0);
        __syncthreads();
    }

#pragma unroll
    for (int ni = 0; ni < 2; ni++) {
        int gcol = col0 + wn + ni * 16 + fr;
        float bb = bias[gcol];
#pragma unroll
        for (int mi = 0; mi < 2; mi++) {
#pragma unroll
            for (int j = 0; j < 4; j++) {
                int grow = row0 + wm + mi * 16 + (l >> 4) * 4 + j;
                if (grow >= M) continue;
                size_t idx = (size_t)grow * HDIM + gcol;
                float v = acc[mi][ni][j] + bb;
                H[idx] = f2bf(v);
                H8[idx] = f2fp8(v);
            }
        }
    }
}

// ---------------------------------------------------------------------------
// Fused layer: per block of 64 nodes,
//   msg = mean_{neighbors} h8_in  (fp8 gather, fp32 acc)  -> LDS bf16 tile
//   acc = msg @ Wt^T  (MFMA, W from L2)
//   h_out = relu(hb_in + acc + bias)  -> bf16 + fp8 mirror
// LAST: no h writes; column-sum into g (atomics) instead.
// ---------------------------------------------------------------------------
template <bool LAST>
__global__ __launch_bounds__(256) void k_agg_gemm(const unsigned char* __restrict__ h8_in,
                                                  const ushort* __restrict__ hb_in,
                                                  const int* __restrict__ row_ptr,
                                                  const int* __restrict__ colx,
                                                  const float* __restrict__ inv_den,
                                                  const ushort* __restrict__ Bt,
                                                  const float* __restrict__ bias,
                                                  ushort* __restrict__ hb_out,
                                                  unsigned char* __restrict__ h8_out,
                                                  float* __restrict__ g,
                                                  int N) {
    __shared__ ushort Ms[64][264];   // row stride 528B (16B-aligned, bank-spread)
    int tid = threadIdx.x;
    int w = tid >> 6, l = tid & 63;
    int row0 = blockIdx.x * 64;

    // ---- Phase 1: gather-average this wave's 16 node rows ----
    const unsigned char* hp = h8_in + (size_t)l * 4;
    for (int i = 0; i < 16; i++) {
        int node = row0 + w * 16 + i;
        float a0 = 0.f, a1 = 0.f, a2 = 0.f, a3 = 0.f;
        float inv = 0.f;
        if (node < N) {
            inv = inv_den[node];
            int s = row_ptr[node], e = row_ptr[node + 1];
            for (int base = s; base < e; base += 64) {
                int cnt = e - base; if (cnt > 64) cnt = 64;
                int cv = (l < cnt) ? colx[base + l] : 0;
                int t = 0;
                for (; t + 1 < cnt; t += 2) {
                    int c0 = __shfl(cv, t);
                    int c1 = __shfl(cv, t + 1);
                    uint32_t v0 = *(const uint32_t*)&hp[(size_t)c0 * HDIM];
                    uint32_t v1 = *(const uint32_t*)&hp[(size_t)c1 * HDIM];
                    auto lo0 = __builtin_amdgcn_cvt_pk_f32_fp8(v0, false);
                    auto hi0 = __builtin_amdgcn_cvt_pk_f32_fp8(v0, true);
                    auto lo1 = __builtin_amdgcn_cvt_pk_f32_fp8(v1, false);
                    auto hi1 = __builtin_amdgcn_cvt_pk_f32_fp8(v1, true);
                    a0 += lo0[0] + lo1[0]; a1 += lo0[1] + lo1[1];
                    a2 += hi0[0] + hi1[0]; a3 += hi0[1] + hi1[1];
                }
                if (t < cnt) {
                    int c0 = __shfl(cv, t);
                    uint32_t v0 = *(const uint32_t*)&hp[(size_t)c0 * HDIM];
                    auto lo0 = __builtin_amdgcn_cvt_pk_f32_fp8(v0, false);
                    auto hi0 = __builtin_amdgcn_cvt_pk_f32_fp8(v0, true);
                    a0 += lo0[0]; a1 += lo0[1]; a2 += hi0[0]; a3 += hi0[1];
                }
            }
        }
        ushort4 o;
        o.x = f2bf(a0 * inv); o.y = f2bf(a1 * inv); o.z = f2bf(a2 * inv); o.w = f2bf(a3 * inv);
        *(ushort4*)&Ms[w * 16 + i][l * 4] = o;
    }
    __syncthreads();

    // ---- Phase 2: 16x256 @ 256x256 MFMA (A from LDS, B from L2) ----
    int fr = l & 15, fkb = (l >> 4) * 8;
    f32x4 acc[16];
#pragma unroll
    for (int ni = 0; ni < 16; ni++) acc[ni] = (f32x4){0.f, 0.f, 0.f, 0.f};
    const ushort* mrow = &Ms[w * 16 + fr][0];
#pragma unroll 2
    for (int kk = 0; kk < 8; kk++) {
        bf16x8 aF = *(const bf16x8*)&mrow[kk * 32 + fkb];
#pragma unroll
        for (int ni = 0; ni < 16; ni++) {
            bf16x8 bF = *(const bf16x8*)&Bt[(size_t)(ni * 16 + fr) * HDIM + kk * 32 + fkb];
            acc[ni] = __builtin_amdgcn_mfma_f32_16x16x32_bf16(aF, bF, acc[ni], 0, 0, 0);
        }
    }

    // ---- Phase 3: epilogue ----
#pragma unroll
    for (int ni = 0; ni < 16; ni++) {
        int gcol = ni * 16 + fr;
        float bb = bias[gcol];
        float csum = 0.f;
#pragma unroll
        for (int j = 0; j < 4; j++) {
            int grow = row0 + w * 16 + (l >> 4) * 4 + j;
            if (grow < N) {
                size_t idx = (size_t)grow * HDIM + gcol;
                float v = acc[ni][j] + bb + bf2f(hb_in[idx]);
                v = fmaxf(v, 0.f);
                if (LAST) {
                    csum += v;
                } else {
                    hb_out[idx] = f2bf(v);
                    h8_out[idx] = f2fp8(v);
                }
            }
        }
        if (LAST) atomicAdd(&g[gcol], csum);
    }
}

// ---------------------------------------------------------------------------
// Tiny MLP head (fp32)
// ---------------------------------------------------------------------------
__global__ __launch_bounds__(256) void k_mlp(const float* __restrict__ g, const float* __restrict__ w1,
                                             const float* __restrict__ b1, const float* __restrict__ w2,
                                             const float* __restrict__ b2, float* __restrict__ out, float invN) {
    __shared__ float gs[256];
    __shared__ float ts[256];
    int f = threadIdx.x;
    gs[f] = g[f] * invN;
    __syncthreads();
    float a = b1[f];
    for (int k = 0; k < 256; k++) a = fmaf(gs[k], w1[k * 256 + f], a);
    ts[f] = fmaxf(a, 0.f);
    __syncthreads();
    float o = b2[f];
    for (int k = 0; k < 256; k++) o = fmaf(ts[k], w2[k * 256 + f], o);
    out[f] = o;
}

// ---------------------------------------------------------------------------
extern "C" void kernel_launch(void* const* d_in, const int* in_sizes, int n_in,
                              void* d_out, int out_size, void* d_ws, size_t ws_size,
                              hipStream_t stream) {
    const float* x      = (const float*)d_in[0];
    const int*   src    = (const int*)d_in[1];
    const int*   dst    = (const int*)d_in[2];
    const float* w_node = (const float*)d_in[3];
    const float* b_node = (const float*)d_in[4];
    const float* w_gnn  = (const float*)d_in[5];
    const float* b_gnn  = (const float*)d_in[6];
    const float* w_p1   = (const float*)d_in[7];
    const float* b_p1   = (const float*)d_in[8];
    const float* w_p2   = (const float*)d_in[9];
    const float* b_p2   = (const float*)d_in[10];
    float* out = (float*)d_out;

    const int N = in_sizes[0] / DNODE;  // 100000
    const int E = in_sizes[1];          // 1600000

    // workspace layout (~175 MB)
    char* w = (char*)d_ws;
    ushort* hbA    = (ushort*)w;        w += (size_t)N * HDIM * 2;
    ushort* hbB    = (ushort*)w;        w += (size_t)N * HDIM * 2;
    unsigned char* h8A = (unsigned char*)w; w += (size_t)N * HDIM;
    unsigned char* h8B = (unsigned char*)w; w += (size_t)N * HDIM;
    ushort* xb     = (ushort*)w;        w += (size_t)N * DNODE * 2;
    ushort* wnt    = (ushort*)w;        w += (size_t)HDIM * DNODE * 2;
    ushort* wgt    = (ushort*)w;        w += (size_t)NLAYERS * HDIM * HDIM * 2;
    int*   deg     = (int*)w;           w += (size_t)N * 4;
    int*   row_ptr = (int*)w;           w += (size_t)(N + 1) * 4;
    int*   cursor  = (int*)w;           w += (size_t)N * 4;
    int*   colx    = (int*)w;           w += (size_t)E * 4;
    float* inv_den = (float*)w;         w += (size_t)N * 4;
    float* g       = (float*)w;         w += 256 * 4;
    int*   bsum    = (int*)w;           w += 256 * 4;
    (void)ws_size; (void)n_in; (void)out_size;

    hipMemsetAsync(deg, 0, (size_t)N * 4, stream);
    hipMemsetAsync(g, 0, 256 * 4, stream);

    // CSR build
    k_deg<<<(E + 255) / 256, 256, 0, stream>>>(dst, deg, E);
    int nb = (N + 2047) / 2048;
    k_scan_partial<<<nb, 256, 0, stream>>>(deg, bsum, N);
    k_scan_bsum<<<1, 64, 0, stream>>>(bsum, nb);
    k_scan_final<<<nb, 256, 0, stream>>>(deg, bsum, row_ptr, cursor, inv_den, N, E);
    k_fill<<<(E + 255) / 256, 256, 0, stream>>>(src, dst, cursor, colx, E);

    // converts
    k_xconv<<<(N * DNODE / 4 + 255) / 256, 256, 0, stream>>>(x, xb, N * DNODE / 4);
    k_wconv<<<DNODE / 16, 256, 0, stream>>>(w_node, wnt, DNODE);
    for (int l = 0; l < NLAYERS; l++)
        k_wconv<<<HDIM / 16, 256, 0, stream>>>(w_gnn + (size_t)l * HDIM * HDIM,
                                               wgt + (size_t)l * HDIM * HDIM, HDIM);

    // node projection -> hbA + h8A
    dim3 gg(HDIM / 64, (N + 63) / 64);
    k_gemm_mfma<<<gg, 256, 0, stream>>>(xb, wnt, b_node, hbA, h8A, N, DNODE);

    // fused GNN layers (ping-pong)
    int nblk = (N + 63) / 64;
    const ushort* hin = hbA; const unsigned char* h8in = h8A;
    ushort* hout = hbB; unsigned char* h8out = h8B;
    for (int l = 0; l < NLAYERS; l++) {
        const ushort* Bt = wgt + (size_t)l * HDIM * HDIM;
        const float* bg = b_gnn + (size_t)l * HDIM;
        if (l < NLAYERS - 1) {
            k_agg_gemm<false><<<nblk, 256, 0, stream>>>(h8in, hin, row_ptr, colx, inv_den,
                                                        Bt, bg, hout, h8out, nullptr, N);
            const ushort* th = hin; hin = hout; hout = (ushort*)th;
            const unsigned char* t8 = h8in; h8in = h8out; h8out = (unsigned char*)t8;
        } else {
            k_agg_gemm<true><<<nblk, 256, 0, stream>>>(h8in, hin, row_ptr, colx, inv_den,
                                                       Bt, bg, nullptr, nullptr, g, N);
        }
    }

    k_mlp<<<1, 256, 0, stream>>>(g, w_p1, b_p1, w_p2, b_p2, out, 1.0f / (float)N);
}

// Round 5
// 717.943 us; speedup vs baseline: 6.3808x; 6.3808x over previous
//
#include <hip/hip_runtime.h>
#include <hip/hip_bf16.h>
#include <cstdint>
#include <cstddef>

#define DNODE 64
#define HDIM 256
#define NLAYERS 3

typedef __attribute__((ext_vector_type(8))) short bf16x8;
typedef __attribute__((ext_vector_type(4))) float f32x4;

__device__ __forceinline__ ushort f2bf(float f) {
    __hip_bfloat16 b = __float2bfloat16(f);
    return *(ushort*)&b;
}
__device__ __forceinline__ float bf2f(ushort u) {
    return __uint_as_float((uint32_t)u << 16);
}
__device__ __forceinline__ unsigned char f2fp8(float f) {
    int p = __builtin_amdgcn_cvt_pk_fp8_f32(f, f, 0, false);
    return (unsigned char)(p & 0xFF);
}

// ---------------------------------------------------------------------------
// CSR build: deg histogram -> exclusive scan -> fill col by atomic cursor
// ---------------------------------------------------------------------------

__global__ __launch_bounds__(256) void k_deg(const int* __restrict__ dst, int* __restrict__ deg, int E) {
    int e = blockIdx.x * 256 + threadIdx.x;
    if (e < E) atomicAdd(&deg[dst[e]], 1);
}

__global__ __launch_bounds__(256) void k_scan_partial(const int* __restrict__ deg, int* __restrict__ bsum, int n) {
    __shared__ int sd[256];
    int tid = threadIdx.x;
    int base = blockIdx.x * 2048 + tid * 8;
    int s = 0;
#pragma unroll
    for (int j = 0; j < 8; j++) {
        int idx = base + j;
        if (idx < n) s += deg[idx];
    }
    sd[tid] = s;
    __syncthreads();
    for (int off = 128; off > 0; off >>= 1) {
        if (tid < off) sd[tid] += sd[tid + off];
        __syncthreads();
    }
    if (tid == 0) bsum[blockIdx.x] = sd[0];
}

__global__ void k_scan_bsum(int* bsum, int nb) {
    if (threadIdx.x == 0 && blockIdx.x == 0) {
        int run = 0;
        for (int i = 0; i < nb; i++) { int v = bsum[i]; bsum[i] = run; run += v; }
    }
}

__global__ __launch_bounds__(256) void k_scan_final(const int* __restrict__ deg, const int* __restrict__ bsum,
                                                    int* __restrict__ row_ptr, int* __restrict__ cursor,
                                                    float* __restrict__ inv_den, int n, int Etot) {
    __shared__ int tsum[256];
    int tid = threadIdx.x;
    int base = blockIdx.x * 2048 + tid * 8;
    int loc[8], dv[8];
    int s = 0;
#pragma unroll
    for (int j = 0; j < 8; j++) {
        int idx = base + j;
        int v = (idx < n) ? deg[idx] : 0;
        dv[j] = v;
        loc[j] = s;
        s += v;
    }
    tsum[tid] = s;
    __syncthreads();
    for (int off = 1; off < 256; off <<= 1) {
        int t = (tid >= off) ? tsum[tid - off] : 0;
        __syncthreads();
        tsum[tid] += t;
        __syncthreads();
    }
    int off0 = bsum[blockIdx.x] + (tid ? tsum[tid - 1] : 0);
#pragma unroll
    for (int j = 0; j < 8; j++) {
        int idx = base + j;
        if (idx < n) {
            int rp = off0 + loc[j];
            row_ptr[idx] = rp;
            cursor[idx] = rp;
            int d = dv[j];
            inv_den[idx] = 1.0f / (float)(d > 0 ? d : 1);
        }
    }
    if (blockIdx.x == 0 && tid == 0) row_ptr[n] = Etot;
}

__global__ __launch_bounds__(256) void k_fill(const int* __restrict__ src, const int* __restrict__ dst,
                                              int* __restrict__ cursor, int* __restrict__ col, int E) {
    int e = blockIdx.x * 256 + threadIdx.x;
    if (e < E) {
        int p = atomicAdd(&cursor[dst[e]], 1);
        col[p] = src[e];
    }
}

// ---------------------------------------------------------------------------
// Converters: x -> bf16;  W[K][256] fp32 -> Wt[256][K] bf16 (B^T for MFMA)
// ---------------------------------------------------------------------------
__global__ __launch_bounds__(256) void k_xconv(const float* __restrict__ x, ushort* __restrict__ xb, int n4) {
    int i = blockIdx.x * 256 + threadIdx.x;
    if (i >= n4) return;
    float4 v = *(const float4*)&x[(size_t)i * 4];
    ushort4 o;
    o.x = f2bf(v.x); o.y = f2bf(v.y); o.z = f2bf(v.z); o.w = f2bf(v.w);
    *(ushort4*)&xb[(size_t)i * 4] = o;
}

__global__ __launch_bounds__(256) void k_wconv(const float* __restrict__ src, ushort* __restrict__ dst, int K) {
    int n = threadIdx.x;
    int k0 = blockIdx.x * 16;
#pragma unroll
    for (int i = 0; i < 16; i++) {
        int k = k0 + i;
        dst[(size_t)n * K + k] = f2bf(src[(size_t)k * 256 + n]);
    }
}

// ---------------------------------------------------------------------------
// Aggregation v3: fp8 gather, one node per 16-lane group (fp8 row = 256B =
// 16 lanes x 16B), 4 groups/wave, 4-deep edge unroll -> 16 loads in flight
// per wave, 100K independent streams, no LDS. fp32 acc, bf16 msg out.
// ---------------------------------------------------------------------------
__device__ __forceinline__ void acc_fp8x16(uint4 v, float* acc) {
    uint32_t d[4] = {v.x, v.y, v.z, v.w};
#pragma unroll
    for (int i = 0; i < 4; i++) {
        auto lo = __builtin_amdgcn_cvt_pk_f32_fp8(d[i], false);
        auto hi = __builtin_amdgcn_cvt_pk_f32_fp8(d[i], true);
        acc[i * 4 + 0] += lo[0];
        acc[i * 4 + 1] += lo[1];
        acc[i * 4 + 2] += hi[0];
        acc[i * 4 + 3] += hi[1];
    }
}

__global__ __launch_bounds__(256) void k_aggregate_fp8(const unsigned char* __restrict__ h8,
                                                       const int* __restrict__ row_ptr,
                                                       const int* __restrict__ colx,
                                                       const float* __restrict__ inv_den,
                                                       ushort* __restrict__ msgb, int N) {
    int tid = threadIdx.x;
    int node = blockIdx.x * 16 + (tid >> 4);
    if (node >= N) return;
    int f = tid & 15;                 // lane within group (feature 16B-slot)
    int gbase = tid & 48;             // group base lane within wave
    const unsigned char* hp = h8 + (size_t)f * 16;

    int s = row_ptr[node], e = row_ptr[node + 1];
    float acc[16] = {};

    for (int base = s; base < e; base += 16) {
        int rem = e - base;
        int cnt = rem > 16 ? 16 : rem;
        int cv = (f < cnt) ? colx[base + f] : 0;
        int t = 0;
        for (; t + 3 < cnt; t += 4) {
            int c0 = __shfl(cv, gbase + t);
            int c1 = __shfl(cv, gbase + t + 1);
            int c2 = __shfl(cv, gbase + t + 2);
            int c3 = __shfl(cv, gbase + t + 3);
            uint4 v0 = *(const uint4*)&hp[(size_t)c0 * HDIM];
            uint4 v1 = *(const uint4*)&hp[(size_t)c1 * HDIM];
            uint4 v2 = *(const uint4*)&hp[(size_t)c2 * HDIM];
            uint4 v3 = *(const uint4*)&hp[(size_t)c3 * HDIM];
            acc_fp8x16(v0, acc);
            acc_fp8x16(v1, acc);
            acc_fp8x16(v2, acc);
            acc_fp8x16(v3, acc);
        }
        for (; t < cnt; t++) {
            int c0 = __shfl(cv, gbase + t);
            uint4 v0 = *(const uint4*)&hp[(size_t)c0 * HDIM];
            acc_fp8x16(v0, acc);
        }
    }

    float inv = inv_den[node];
    ushort o[16];
#pragma unroll
    for (int k = 0; k < 16; k++) o[k] = f2bf(acc[k] * inv);
    ushort* mp = &msgb[(size_t)node * HDIM + f * 16];
    *(uint4*)&mp[0] = *(uint4*)&o[0];
    *(uint4*)&mp[8] = *(uint4*)&o[8];
}

// ---------------------------------------------------------------------------
// bf16 MFMA GEMM: H[M][256] = act( (ADD?H:0) + A[M][K] @ Bt[256][K]^T + bias )
// 64x64 tile, 4 waves, 16x16x32 MFMA, fp32 accum. In-place safe on H.
// W8: also write fp8 mirror H8.
// ---------------------------------------------------------------------------
template <bool ADD, bool RELU, bool W8>
__global__ __launch_bounds__(256) void k_gemm_mfma(const ushort* __restrict__ A,
                                                   const ushort* __restrict__ Bt,
                                                   const float* __restrict__ bias,
                                                   ushort* __restrict__ H,
                                                   unsigned char* __restrict__ H8,
                                                   int M, int K) {
    __shared__ ushort As[64][40];
    __shared__ ushort Bs[64][40];
    int tid = threadIdx.x;
    int w = tid >> 6, l = tid & 63;
    int row0 = blockIdx.y * 64, col0 = blockIdx.x * 64;
    int sr = tid >> 2, sc = (tid & 3) * 8;
    int wm = (w >> 1) * 32, wn = (w & 1) * 32;
    int fr = l & 15, fk = (l >> 4) * 8;
    f32x4 acc[2][2] = {};

    for (int k0 = 0; k0 < K; k0 += 32) {
        bf16x8 av = {0, 0, 0, 0, 0, 0, 0, 0};
        int gr = row0 + sr;
        if (gr < M) av = *(const bf16x8*)&A[(size_t)gr * K + k0 + sc];
        *(bf16x8*)&As[sr][sc] = av;
        bf16x8 bv = *(const bf16x8*)&Bt[(size_t)(col0 + sr) * K + k0 + sc];
        *(bf16x8*)&Bs[sr][sc] = bv;
        __syncthreads();
        bf16x8 af[2], bf[2];
#pragma unroll
        for (int mi = 0; mi < 2; mi++) af[mi] = *(const bf16x8*)&As[wm + mi * 16 + fr][fk];
#pragma unroll
        for (int ni = 0; ni < 2; ni++) bf[ni] = *(const bf16x8*)&Bs[wn + ni * 16 + fr][fk];
#pragma unroll
        for (int mi = 0; mi < 2; mi++)
#pragma unroll
            for (int ni = 0; ni < 2; ni++)
                acc[mi][ni] = __builtin_amdgcn_mfma_f32_16x16x32_bf16(af[mi], bf[ni], acc[mi][ni], 0, 0, 0);
        __syncthreads();
    }

#pragma unroll
    for (int ni = 0; ni < 2; ni++) {
        int gcol = col0 + wn + ni * 16 + fr;
        float bb = bias[gcol];
#pragma unroll
        for (int mi = 0; mi < 2; mi++) {
#pragma unroll
            for (int j = 0; j < 4; j++) {
                int grow = row0 + wm + mi * 16 + (l >> 4) * 4 + j;
                if (grow >= M) continue;
                size_t idx = (size_t)grow * HDIM + gcol;
                float v = acc[mi][ni][j] + bb;
                if (ADD) v += bf2f(H[idx]);
                if (RELU) v = fmaxf(v, 0.f);
                H[idx] = f2bf(v);
                if (W8) H8[idx] = f2fp8(v);
            }
        }
    }
}

// ---------------------------------------------------------------------------
// Column sum (bf16 in, fp32 atomics) + tiny MLP head (fp32)
// ---------------------------------------------------------------------------
__global__ __launch_bounds__(256) void k_colsum_bf(const ushort* __restrict__ hb, float* __restrict__ g, int n) {
    int f = threadIdx.x;
    float acc = 0.f;
    for (int i = blockIdx.x; i < n; i += gridDim.x) acc += bf2f(hb[(size_t)i * HDIM + f]);
    atomicAdd(&g[f], acc);
}

__global__ __launch_bounds__(256) void k_mlp(const float* __restrict__ g, const float* __restrict__ w1,
                                             const float* __restrict__ b1, const float* __restrict__ w2,
                                             const float* __restrict__ b2, float* __restrict__ out, float invN) {
    __shared__ float gs[256];
    __shared__ float ts[256];
    int f = threadIdx.x;
    gs[f] = g[f] * invN;
    __syncthreads();
    float a = b1[f];
    for (int k = 0; k < 256; k++) a = fmaf(gs[k], w1[k * 256 + f], a);
    ts[f] = fmaxf(a, 0.f);
    __syncthreads();
    float o = b2[f];
    for (int k = 0; k < 256; k++) o = fmaf(ts[k], w2[k * 256 + f], o);
    out[f] = o;
}

// ---------------------------------------------------------------------------
extern "C" void kernel_launch(void* const* d_in, const int* in_sizes, int n_in,
                              void* d_out, int out_size, void* d_ws, size_t ws_size,
                              hipStream_t stream) {
    const float* x      = (const float*)d_in[0];
    const int*   src    = (const int*)d_in[1];
    const int*   dst    = (const int*)d_in[2];
    const float* w_node = (const float*)d_in[3];
    const float* b_node = (const float*)d_in[4];
    const float* w_gnn  = (const float*)d_in[5];
    const float* b_gnn  = (const float*)d_in[6];
    const float* w_p1   = (const float*)d_in[7];
    const float* b_p1   = (const float*)d_in[8];
    const float* w_p2   = (const float*)d_in[9];
    const float* b_p2   = (const float*)d_in[10];
    float* out = (float*)d_out;

    const int N = in_sizes[0] / DNODE;  // 100000
    const int E = in_sizes[1];          // 1600000

    // workspace layout (~155 MB)
    char* w = (char*)d_ws;
    ushort* hb     = (ushort*)w;            w += (size_t)N * HDIM * 2;
    ushort* msgb   = (ushort*)w;            w += (size_t)N * HDIM * 2;
    unsigned char* h8 = (unsigned char*)w;  w += (size_t)N * HDIM;
    ushort* xb     = (ushort*)w;            w += (size_t)N * DNODE * 2;
    ushort* wnt    = (ushort*)w;            w += (size_t)HDIM * DNODE * 2;
    ushort* wgt    = (ushort*)w;            w += (size_t)NLAYERS * HDIM * HDIM * 2;
    int*   deg     = (int*)w;               w += (size_t)N * 4;
    int*   row_ptr = (int*)w;               w += (size_t)(N + 1) * 4;
    int*   cursor  = (int*)w;               w += (size_t)N * 4;
    int*   colx    = (int*)w;               w += (size_t)E * 4;
    float* inv_den = (float*)w;             w += (size_t)N * 4;
    float* g       = (float*)w;             w += 256 * 4;
    int*   bsum    = (int*)w;               w += 256 * 4;
    (void)ws_size; (void)n_in; (void)out_size;

    hipMemsetAsync(deg, 0, (size_t)N * 4, stream);
    hipMemsetAsync(g, 0, 256 * 4, stream);

    // CSR build
    k_deg<<<(E + 255) / 256, 256, 0, stream>>>(dst, deg, E);
    int nb = (N + 2047) / 2048;
    k_scan_partial<<<nb, 256, 0, stream>>>(deg, bsum, N);
    k_scan_bsum<<<1, 64, 0, stream>>>(bsum, nb);
    k_scan_final<<<nb, 256, 0, stream>>>(deg, bsum, row_ptr, cursor, inv_den, N, E);
    k_fill<<<(E + 255) / 256, 256, 0, stream>>>(src, dst, cursor, colx, E);

    // converts
    k_xconv<<<(N * DNODE / 4 + 255) / 256, 256, 0, stream>>>(x, xb, N * DNODE / 4);
    k_wconv<<<DNODE / 16, 256, 0, stream>>>(w_node, wnt, DNODE);
    for (int l = 0; l < NLAYERS; l++)
        k_wconv<<<HDIM / 16, 256, 0, stream>>>(w_gnn + (size_t)l * HDIM * HDIM,
                                               wgt + (size_t)l * HDIM * HDIM, HDIM);

    // node projection -> hb + h8
    dim3 gg(HDIM / 64, (N + 63) / 64);
    k_gemm_mfma<false, false, true><<<gg, 256, 0, stream>>>(xb, wnt, b_node, hb, h8, N, DNODE);

    // GNN layers: aggregate (fp8 gather) then GEMM (in-place residual)
    int nagg = (N + 15) / 16;
    for (int l = 0; l < NLAYERS; l++) {
        k_aggregate_fp8<<<nagg, 256, 0, stream>>>(h8, row_ptr, colx, inv_den, msgb, N);
        const ushort* Bt = wgt + (size_t)l * HDIM * HDIM;
        const float* bg = b_gnn + (size_t)l * HDIM;
        if (l < NLAYERS - 1)
            k_gemm_mfma<true, true, true><<<gg, 256, 0, stream>>>(msgb, Bt, bg, hb, h8, N, HDIM);
        else
            k_gemm_mfma<true, true, false><<<gg, 256, 0, stream>>>(msgb, Bt, bg, hb, nullptr, N, HDIM);
    }

    k_colsum_bf<<<512, 256, 0, stream>>>(hb, g, N);
    k_mlp<<<1, 256, 0, stream>>>(g, w_p1, b_p1, w_p2, b_p2, out, 1.0f / (float)N);
}